// Round 14
// baseline (436.428 us; speedup 1.0000x reference)
//
#include <hip/hip_runtime.h>
#include <hip/hip_fp16.h>

#define NREL 3
#define EPB 2048                    // edges per partition block
#define BKT_SHIFT 12                // 4096 nodes per bucket (NB<=256 for n<=1M)
#define BKT_NODES (1 << BKT_SHIFT)
#define BKT_MASK (BKT_NODES - 1)
#define X1S 32                      // x1 row stride in halfs (64B-aligned rows)

// ---------------------------------------------------------------------------
__device__ __forceinline__ void unpack8(uint4 v, float* o) {
    *(float2*)(o+0) = __half22float2(*(__half2*)&v.x);
    *(float2*)(o+2) = __half22float2(*(__half2*)&v.y);
    *(float2*)(o+4) = __half22float2(*(__half2*)&v.z);
    *(float2*)(o+6) = __half22float2(*(__half2*)&v.w);
}
__device__ __forceinline__ unsigned pack2(float a, float b) {
    __half2 h = __floats2half2_rn(a, b);
    return *(unsigned*)&h;
}

// ===========================================================================
// Node-type tables for layer 0 (fp32; L2-resident)
// ===========================================================================
__global__ void k_tables2(const float* __restrict__ size_emb,
                          const float* __restrict__ code_emb,
                          const float* __restrict__ w0,
                          const float* __restrict__ root0,
                          const float* __restrict__ b0,
                          float* __restrict__ T, float* __restrict__ Troot,
                          int ns, int nc)
{
    int ntype = ns * nc;
    int tid = blockIdx.x * blockDim.x + threadIdx.x;
    int tot1 = NREL * ntype * 24;
    if (tid < tot1) {
        int d = tid % 24;
        int sc = (tid / 24) % ntype;
        int r = tid / (24 * ntype);
        int sz = sc / nc, cd = sc % nc;
        float a = 0.f;
        #pragma unroll
        for (int k = 0; k < 4; ++k)  a += size_emb[sz*4+k] * w0[(r*36+k)*24+d];
        for (int k = 0; k < 32; ++k) a += code_emb[cd*32+k] * w0[(r*36+4+k)*24+d];
        T[tid] = a;
    } else if (tid < tot1 + ntype * 24) {
        int t = tid - tot1;
        int d = t % 24;
        int sc = t / 24;
        int sz = sc / nc, cd = sc % nc;
        float a = b0[d];
        #pragma unroll
        for (int k = 0; k < 4; ++k)  a += size_emb[sz*4+k] * root0[k*24+d];
        for (int k = 0; k < 32; ++k) a += code_emb[cd*32+k] * root0[(4+k)*24+d];
        Troot[t] = a;
    }
}

__global__ void k_key(const int* __restrict__ x_size, const int* __restrict__ x_code,
                      int* __restrict__ key2, int n, int nc)
{
    int i = blockIdx.x * blockDim.x + threadIdx.x;
    if (i < n) key2[i] = x_size[i] * nc + x_code[i];
}

// ===========================================================================
// Atomic-free CSR build (device-scope-atomic-free; LDS atomics only):
//  k_hist    : per-block bucket histogram -> histT[bucket][block]
//  kscan1/2/3: exclusive scan of histT -> exact (block,bucket) offsets
//  k_scatter : LDS-ranked scatter into bucket-partitioned tmp (uint2);
//              resolves key2[src] here (977-block TLP hides gather latency)
//  k_csr     : per-bucket LDS count+scan -> rowptr slice + edges (4B) +
//              edges0 (2B: tkey|rel<<12) for layer 0
// tmp.x = src(20) | rel(2)<<20 ; tmp.y = dstlocal(12) | tkey(12)<<12 | rel(2)<<24
// ===========================================================================
__global__ void __launch_bounds__(256) k_hist(
    const int* __restrict__ dst, int* __restrict__ histT, int E, int NB, int NBK)
{
    __shared__ int h[256];
    int bl = blockIdx.x;
    h[threadIdx.x] = 0;
    __syncthreads();
    int base = bl * EPB;
    #pragma unroll
    for (int it = 0; it < EPB / 256; ++it) {
        int e = base + it * 256 + (int)threadIdx.x;
        if (e < E) atomicAdd(&h[dst[e] >> BKT_SHIFT], 1);
    }
    __syncthreads();
    if ((int)threadIdx.x < NB)
        histT[threadIdx.x * NBK + bl] = h[threadIdx.x];
}

__global__ void kscan1(const int* __restrict__ arr, int* __restrict__ partials, int m)
{
    __shared__ int s[256];
    int t = threadIdx.x;
    int base = blockIdx.x * 1024 + t * 4;
    int sum = 0;
    #pragma unroll
    for (int j = 0; j < 4; ++j) {
        int i = base + j;
        if (i < m) sum += arr[i];
    }
    s[t] = sum; __syncthreads();
    for (int off = 128; off > 0; off >>= 1) {
        if (t < off) s[t] += s[t + off];
        __syncthreads();
    }
    if (t == 0) partials[blockIdx.x] = s[0];
}

__global__ void kscan2(int* partials, int np)
{
    __shared__ int s[1024];
    int t = threadIdx.x;
    int v = (t < np) ? partials[t] : 0;
    s[t] = v; __syncthreads();
    for (int off = 1; off < 1024; off <<= 1) {
        int a = (t >= off) ? s[t - off] : 0;
        __syncthreads();
        s[t] += a; __syncthreads();
    }
    if (t < np) partials[t] = s[t] - v;  // exclusive
}

__global__ void kscan3(int* __restrict__ arr, const int* __restrict__ partials, int m)
{
    __shared__ int s[256];
    int t = threadIdx.x;
    int base = blockIdx.x * 1024 + t * 4;
    int d0 = 0, d1 = 0, d2 = 0, d3 = 0;
    if (base + 0 < m) d0 = arr[base+0];
    if (base + 1 < m) d1 = arr[base+1];
    if (base + 2 < m) d2 = arr[base+2];
    if (base + 3 < m) d3 = arr[base+3];
    int tsum = d0 + d1 + d2 + d3;
    s[t] = tsum; __syncthreads();
    for (int off = 1; off < 256; off <<= 1) {
        int a = (t >= off) ? s[t - off] : 0;
        __syncthreads();
        s[t] += a; __syncthreads();
    }
    int excl = s[t] - tsum + partials[blockIdx.x];
    if (base + 0 < m) arr[base+0] = excl;
    if (base + 1 < m) arr[base+1] = excl + d0;
    if (base + 2 < m) arr[base+2] = excl + d0 + d1;
    if (base + 3 < m) arr[base+3] = excl + d0 + d1 + d2;
}

__global__ void __launch_bounds__(256) k_scatter(
    const int* __restrict__ src, const int* __restrict__ dst,
    const int* __restrict__ et, const int* __restrict__ key2,
    const int* __restrict__ offT,
    uint2* __restrict__ tmp, int E, int NB, int NBK)
{
    __shared__ int h[256];
    int bl = blockIdx.x;
    h[threadIdx.x] = 0;
    __syncthreads();
    int base = bl * EPB;
    #pragma unroll
    for (int it = 0; it < EPB / 256; ++it) {
        int e = base + it * 256 + (int)threadIdx.x;
        if (e < E) {
            int d = dst[e];
            int b = d >> BKT_SHIFT;
            int s = src[e];
            int r = et[e];
            int tk = key2[s];
            int rank = atomicAdd(&h[b], 1);
            int pos = offT[b * NBK + bl] + rank;
            tmp[pos] = make_uint2((unsigned)s | ((unsigned)r << 20),
                                  (unsigned)(d & BKT_MASK)
                                | ((unsigned)tk << 12)
                                | ((unsigned)r << 24));
        }
    }
}

__global__ void __launch_bounds__(256) k_csr(
    const uint2* __restrict__ tmp, const int* __restrict__ offT,
    int* __restrict__ rowptr, unsigned* __restrict__ edges,
    unsigned short* __restrict__ edges0,
    int n, int E, int NB, int NBK)
{
    __shared__ int cnt[BKT_NODES];
    __shared__ int fil[BKT_NODES];
    __shared__ int ws[256];
    int b = blockIdx.x;
    int eb = offT[b * NBK];
    int ee = (b + 1 < NB) ? offT[(b + 1) * NBK] : E;
    int node0 = b << BKT_SHIFT;
    int t = threadIdx.x;

    for (int l = t; l < BKT_NODES; l += 256) cnt[l] = 0;
    __syncthreads();
    for (int e = eb + t; e < ee; e += 256)
        atomicAdd(&cnt[tmp[e].y & BKT_MASK], 1);
    __syncthreads();

    // block-exclusive scan of cnt[4096]: 16 per thread + scan of 256 sums
    {
        int base16 = t * 16;
        int sum = 0;
        #pragma unroll
        for (int j = 0; j < 16; ++j) sum += cnt[base16 + j];
        ws[t] = sum; __syncthreads();
        for (int off = 1; off < 256; off <<= 1) {
            int a = (t >= off) ? ws[t - off] : 0;
            __syncthreads();
            ws[t] += a; __syncthreads();
        }
        int run = ws[t] - sum;
        #pragma unroll
        for (int j = 0; j < 16; ++j) {
            int c = cnt[base16 + j];
            fil[base16 + j] = run;
            run += c;
        }
    }
    __syncthreads();

    // rowptr slice (coalesced); completes before fil is mutated below
    for (int l = t; l < BKT_NODES; l += 256) {
        int node = node0 + l;
        if (node < n) rowptr[node] = eb + fil[l];
    }
    if (b == NB - 1 && t == 0) rowptr[n] = E;
    __syncthreads();

    // final placement into L1/L2-hot window
    for (int e = eb + t; e < ee; e += 256) {
        uint2 w = tmp[e];
        int l = w.y & BKT_MASK;
        int pos = eb + atomicAdd(&fil[l], 1);
        edges[pos]  = w.x;                                // src | rel<<20
        edges0[pos] = (unsigned short)(w.y >> 12);        // tkey | rel<<12 (14b)
    }
}

// ===========================================================================
// Layer 0, pull: edges0 (2B) pre-resolves type+rel -> no key2/src access,
// single L2-hot T-row load per edge.  Output fp16, rows padded to 64B.
// ===========================================================================
__global__ void __launch_bounds__(256) k_layer0_pull(
    const int* __restrict__ key2,
    const int* __restrict__ rowptr, const unsigned short* __restrict__ edges0,
    const float* __restrict__ T,      // [3*ntype*24]
    const float* __restrict__ Troot,  // [ntype*24]
    __half* __restrict__ xout, int n, int ntype)
{
    int i = blockIdx.x * blockDim.x + threadIdx.x;
    if (i >= n) return;

    int e0 = rowptr[i], e1 = rowptr[i+1];
    int c0 = 0, c1 = 0, c2 = 0;
    for (int e = e0; e < e1; ++e) {
        int r = edges0[e] >> 12;
        c0 += (r == 0); c1 += (r == 1); c2 += (r == 2);
    }
    float inv0 = 1.f / fmaxf((float)c0, 1.f);
    float inv1 = 1.f / fmaxf((float)c1, 1.f);
    float inv2 = 1.f / fmaxf((float)c2, 1.f);

    float acc[24];
    {
        const float4* tr = (const float4*)(Troot + (size_t)key2[i] * 24);
        #pragma unroll
        for (int q = 0; q < 6; ++q) {
            float4 v = tr[q];
            acc[q*4+0]=v.x; acc[q*4+1]=v.y; acc[q*4+2]=v.z; acc[q*4+3]=v.w;
        }
    }
    for (int e = e0; e < e1; ++e) {
        unsigned short sl = edges0[e];
        int tk = sl & 0xFFF;
        int r  = sl >> 12;
        float w = (r == 0) ? inv0 : ((r == 1) ? inv1 : inv2);
        const float4* trow = (const float4*)(T + ((size_t)r * ntype + tk) * 24);
        #pragma unroll
        for (int q = 0; q < 6; ++q) {
            float4 v = trow[q];
            acc[q*4+0] = fmaf(v.x, w, acc[q*4+0]);
            acc[q*4+1] = fmaf(v.y, w, acc[q*4+1]);
            acc[q*4+2] = fmaf(v.z, w, acc[q*4+2]);
            acc[q*4+3] = fmaf(v.w, w, acc[q*4+3]);
        }
    }
    unsigned ow[16];
    #pragma unroll
    for (int q = 0; q < 12; ++q)
        ow[q] = pack2(fmaxf(acc[2*q], 0.f), fmaxf(acc[2*q+1], 0.f));
    ow[12] = ow[13] = ow[14] = ow[15] = 0;               // pad to 64B
    uint4* op = (uint4*)(xout + (size_t)i * X1S);
    #pragma unroll
    for (int q = 0; q < 4; ++q) op[q] = ((uint4*)ow)[q];
}

// ===========================================================================
// Layers 1..3, pull: fp16 gathers (DINS = input row stride), fp32 accumulate.
// ===========================================================================
template<int DIN, int DINS, int DOUT, bool FINAL>
__global__ void __launch_bounds__(256) k_layer_pull(
    const __half* __restrict__ xin,
    __half* __restrict__ xout,
    const int* __restrict__ rowptr, const unsigned* __restrict__ edges,
    const float* __restrict__ W,     // [3,DIN,DOUT]
    const float* __restrict__ root,  // [DIN,DOUT]
    const float* __restrict__ bias,  // [DOUT]
    const float* __restrict__ linw,  // [4,2]
    const float* __restrict__ linb,  // [2]
    float* __restrict__ finout, int n)
{
    int j = blockIdx.x * blockDim.x + threadIdx.x;
    if (j >= n) return;

    float a0[DIN], a1[DIN], a2[DIN];
    #pragma unroll
    for (int k = 0; k < DIN; ++k) { a0[k] = 0.f; a1[k] = 0.f; a2[k] = 0.f; }
    int c0 = 0, c1 = 0, c2 = 0;

    int e0 = rowptr[j], e1 = rowptr[j+1];
    for (int e = e0; e < e1; ++e) {
        unsigned sl = edges[e];
        int s = sl & 0xFFFFF;
        int r = sl >> 20;
        const uint4* p = (const uint4*)(xin + (size_t)s * DINS);
        float xs[DIN];
        #pragma unroll
        for (int q = 0; q < DIN/8; ++q) unpack8(p[q], xs + q*8);
        if (r == 0) {
            ++c0;
            #pragma unroll
            for (int k = 0; k < DIN; ++k) a0[k] += xs[k];
        } else if (r == 1) {
            ++c1;
            #pragma unroll
            for (int k = 0; k < DIN; ++k) a1[k] += xs[k];
        } else {
            ++c2;
            #pragma unroll
            for (int k = 0; k < DIN; ++k) a2[k] += xs[k];
        }
    }
    {
        float inv0 = 1.f / fmaxf((float)c0, 1.f);
        float inv1 = 1.f / fmaxf((float)c1, 1.f);
        float inv2 = 1.f / fmaxf((float)c2, 1.f);
        #pragma unroll
        for (int k = 0; k < DIN; ++k) { a0[k] *= inv0; a1[k] *= inv1; a2[k] *= inv2; }
    }

    float o[DOUT];
    #pragma unroll
    for (int d = 0; d < DOUT; ++d) o[d] = bias[d];

    {   // self/root term
        const uint4* p = (const uint4*)(xin + (size_t)j * DINS);
        float xi[DIN];
        #pragma unroll
        for (int q = 0; q < DIN/8; ++q) unpack8(p[q], xi + q*8);
        #pragma unroll
        for (int k = 0; k < DIN; ++k) {
            #pragma unroll
            for (int d = 0; d < DOUT; ++d)
                o[d] = fmaf(xi[k], root[k*DOUT + d], o[d]);
        }
    }
    #pragma unroll
    for (int k = 0; k < DIN; ++k) {
        #pragma unroll
        for (int d = 0; d < DOUT; ++d)
            o[d] = fmaf(a0[k], W[(0*DIN + k)*DOUT + d], o[d]);
    }
    #pragma unroll
    for (int k = 0; k < DIN; ++k) {
        #pragma unroll
        for (int d = 0; d < DOUT; ++d)
            o[d] = fmaf(a1[k], W[(1*DIN + k)*DOUT + d], o[d]);
    }
    #pragma unroll
    for (int k = 0; k < DIN; ++k) {
        #pragma unroll
        for (int d = 0; d < DOUT; ++d)
            o[d] = fmaf(a2[k], W[(2*DIN + k)*DOUT + d], o[d]);
    }
    #pragma unroll
    for (int d = 0; d < DOUT; ++d) o[d] = fmaxf(o[d], 0.f);

    if (FINAL) {
        float o0 = linb[0], o1 = linb[1];
        #pragma unroll
        for (int k = 0; k < 4; ++k) {
            o0 = fmaf(o[k], linw[k*2+0], o0);
            o1 = fmaf(o[k], linw[k*2+1], o1);
        }
        *(float2*)(finout + (size_t)j * 2) = make_float2(o0, o1);
    } else {
        unsigned ow[DOUT/2];
        #pragma unroll
        for (int q = 0; q < DOUT/2; ++q) ow[q] = pack2(o[2*q], o[2*q+1]);
        uint4* op = (uint4*)(xout + (size_t)j * DOUT);
        #pragma unroll
        for (int q = 0; q < DOUT/8; ++q) op[q] = ((uint4*)ow)[q];
    }
}

// ===========================================================================
extern "C" void kernel_launch(void* const* d_in, const int* in_sizes, int n_in,
                              void* d_out, int out_size, void* d_ws, size_t ws_size,
                              hipStream_t stream)
{
    const int*   x_code    = (const int*)d_in[0];
    const int*   x_size    = (const int*)d_in[1];
    const int*   edge_index= (const int*)d_in[2];
    const int*   edge_type = (const int*)d_in[3];
    const float* size_emb  = (const float*)d_in[4];
    const float* code_emb  = (const float*)d_in[5];
    const float* w0 = (const float*)d_in[6];  const float* root0 = (const float*)d_in[7];  const float* b0 = (const float*)d_in[8];
    const float* w1 = (const float*)d_in[9];  const float* root1 = (const float*)d_in[10]; const float* b1 = (const float*)d_in[11];
    const float* w2 = (const float*)d_in[12]; const float* root2 = (const float*)d_in[13]; const float* b2 = (const float*)d_in[14];
    const float* w3 = (const float*)d_in[15]; const float* root3 = (const float*)d_in[16]; const float* b3 = (const float*)d_in[17];
    const float* lin_w = (const float*)d_in[18];
    const float* lin_b = (const float*)d_in[19];

    int n  = in_sizes[0];
    int E  = in_sizes[3];
    int ns = in_sizes[4] / 4;    // 15
    int nc = in_sizes[5] / 32;   // 202
    int ntype = ns * nc;         // 3030
    const int* esrc = edge_index;
    const int* edst = edge_index + E;

    int NB  = (n + BKT_MASK) >> BKT_SHIFT;     // buckets (245 for 1M; <=256)
    int NBK = (E + EPB - 1) / EPB;             // partition blocks (977)
    int m   = NB * NBK;                        // histT elements (~240K)

    // workspace carve-up (~135 MB)
    char* ws = (char*)d_ws;
    size_t off = 0;
    auto alloc = [&](size_t bytes) -> void* {
        void* p = ws + off;
        off = (off + bytes + 255) & ~(size_t)255;
        return p;
    };
    __half*         bufA   = (__half*)        alloc((size_t)n * X1S * 2);  // x1 (padded), later x3
    __half*         bufB   = (__half*)        alloc((size_t)n * 16 * 2);   // x2
    int*            rowptr = (int*)           alloc(((size_t)n + 1) * 4);
    unsigned*       edges  = (unsigned*)      alloc((size_t)E * 4);        // src|rel
    unsigned short* edges0 = (unsigned short*)alloc((size_t)E * 2);        // tkey|rel
    uint2*          tmp    = (uint2*)         alloc((size_t)E * 8);
    int*            histT  = (int*)           alloc((size_t)m * 4);
    int*            key2   = (int*)           alloc((size_t)n * 4);
    int*            partials=(int*)           alloc(4096 * 4);
    float*          T      = (float*)         alloc((size_t)NREL * ntype * 24 * 4);
    float*          Troot  = (float*)         alloc((size_t)ntype * 24 * 4);

    const int tb = 256;
    int tableThreads = NREL*ntype*24 + ntype*24;
    k_tables2<<<(tableThreads + tb - 1)/tb, tb, 0, stream>>>(
        size_emb, code_emb, w0, root0, b0, T, Troot, ns, nc);
    k_key<<<(n + tb - 1)/tb, tb, 0, stream>>>(x_size, x_code, key2, n, nc);

    // ---- CSR build ----
    k_hist<<<NBK, tb, 0, stream>>>(edst, histT, E, NB, NBK);
    int nblk = (m + 1023) / 1024;              // ~234 (<=1024)
    kscan1<<<nblk, tb, 0, stream>>>(histT, partials, m);
    kscan2<<<1, 1024, 0, stream>>>(partials, nblk);
    kscan3<<<nblk, tb, 0, stream>>>(histT, partials, m);
    k_scatter<<<NBK, tb, 0, stream>>>(esrc, edst, edge_type, key2, histT, tmp, E, NB, NBK);
    k_csr<<<NB, tb, 0, stream>>>(tmp, histT, rowptr, edges, edges0, n, E, NB, NBK);

    // ---- layers ----
    int g256 = (n + 255) / 256;
    k_layer0_pull<<<g256, tb, 0, stream>>>(key2, rowptr, edges0, T, Troot, bufA, n, ntype);
    k_layer_pull<24,X1S,16,false><<<g256, tb, 0, stream>>>(bufA, bufB, rowptr, edges,
                                                 w1, root1, b1, nullptr, nullptr, nullptr, n);
    k_layer_pull<16,16, 8,false><<<g256, tb, 0, stream>>>(bufB, bufA, rowptr, edges,
                                                 w2, root2, b2, nullptr, nullptr, nullptr, n);
    k_layer_pull< 8, 8, 4,true ><<<g256, tb, 0, stream>>>(bufA, nullptr, rowptr, edges,
                                                 w3, root3, b3, lin_w, lin_b, (float*)d_out, n);
}